// Round 9
// baseline (370.865 us; speedup 1.0000x reference)
//
#include <hip/hip_runtime.h>
#include <hip/hip_bf16.h>

// Problem constants
#define Bb 256
#define Tt 128
#define Nn 512
#define Hh 128
// 4H = 512

typedef __attribute__((ext_vector_type(4))) float floatx4;
typedef __attribute__((ext_vector_type(8))) short short8;
typedef _Float16 h2v_t __attribute__((ext_vector_type(2)));

__device__ __forceinline__ unsigned short f2bf(float f) {
  unsigned u = __float_as_uint(f);
  u += 0x7fffu + ((u >> 16) & 1u);   // round-to-nearest-even
  return (unsigned short)(u >> 16);
}

__device__ __forceinline__ float sigmoid_fast(float x) {
  return __builtin_amdgcn_rcpf(1.f + __expf(-x));
}
__device__ __forceinline__ float tanh_fast(float x) {
  float e = __expf(2.f * x);                       // inf-safe
  return 1.f - 2.f * __builtin_amdgcn_rcpf(e + 1.f);
}

__device__ __forceinline__ void async_load16(const void* g, void* lds) {
  __builtin_amdgcn_global_load_lds(
      (const __attribute__((address_space(1))) unsigned int*)g,
      (__attribute__((address_space(3))) unsigned int*)lds, 16, 0, 0);
}

// 2-MAC-per-lane fp16 dot with fp32 accumulate (v_dot2_f32_f16).
#if __has_builtin(__builtin_amdgcn_fdot2)
#define FDOT2(a, b, c) __builtin_amdgcn_fdot2((a), (b), (c), false)
#else
__device__ __forceinline__ float fdot2_sw(h2v_t a, h2v_t b, float c) {
  return fmaf((float)a.x, (float)b.x, fmaf((float)a.y, (float)b.y, (c)));
}
#define FDOT2(a, b, c) fdot2_sw((a), (b), (c))
#endif

// Quad-permute via DPP. 0xB1 = [1,0,3,2] (xor 1); 0x4E = [2,3,0,1] (xor 2).
template <int CTRL>
__device__ __forceinline__ float qperm(float x) {
#if __has_builtin(__builtin_amdgcn_update_dpp)
  return __uint_as_float((unsigned)__builtin_amdgcn_update_dpp(
      0, (int)__float_as_uint(x), CTRL, 0xf, 0xf, true));
#else
  return __shfl_xor(x, CTRL == 0xB1 ? 1 : 2, 64);
#endif
}

// ---------------------------------------------------------------------------
// Kernel 1: convert w_ih to bf16, precompute bias = b_ih + b_hh
// ---------------------------------------------------------------------------
__global__ void prep_kernel(const float* __restrict__ w_ih,
                            const float* __restrict__ b_ih,
                            const float* __restrict__ b_hh,
                            unsigned short* __restrict__ wb,
                            float* __restrict__ bias) {
  int i = blockIdx.x * 256 + threadIdx.x;
  if (i < 4 * Hh * Nn) wb[i] = f2bf(w_ih[i]);
  if (i < 4 * Hh) bias[i] = b_ih[i] + b_hh[i];
}

// ---------------------------------------------------------------------------
// Kernel 2: alpha = softmax_n( X^T w_x )  (R4/R8-verified, coalesced)
// ---------------------------------------------------------------------------
__global__ __launch_bounds__(512) void alpha_kernel(const float* __restrict__ X,
                                                    const float* __restrict__ attn_w,
                                                    float* __restrict__ alpha) {
  int b = blockIdx.x;
  int tid = threadIdx.x;
  int c = tid & 127;
  int tp = tid >> 7;
  const float4* Xb = (const float4*)(X + (size_t)b * Tt * Nn) + c;
  const float* wx = attn_w + 2 * Hh;

  float4 acc = {0.f, 0.f, 0.f, 0.f};
#pragma unroll 8
  for (int tt = 0; tt < 32; ++tt) {
    int t = tp * 32 + tt;
    float4 x = Xb[(size_t)t * 128];
    float w = wx[t];
    acc.x = fmaf(x.x, w, acc.x);
    acc.y = fmaf(x.y, w, acc.y);
    acc.z = fmaf(x.z, w, acc.z);
    acc.w = fmaf(x.w, w, acc.w);
  }

  __shared__ float4 s4[512];
  __shared__ float sred[128];
  s4[tid] = acc;
  __syncthreads();

  float4 sc = {0.f, 0.f, 0.f, 0.f};
  if (tid < 128) {
    float4 a = s4[tid], b2 = s4[tid + 128], c2 = s4[tid + 256], d = s4[tid + 384];
    sc.x = a.x + b2.x + c2.x + d.x;
    sc.y = a.y + b2.y + c2.y + d.y;
    sc.z = a.z + b2.z + c2.z + d.z;
    sc.w = a.w + b2.w + c2.w + d.w;
    sred[tid] = fmaxf(fmaxf(sc.x, sc.y), fmaxf(sc.z, sc.w));
  }
  __syncthreads();
  for (int s = 64; s > 0; s >>= 1) {
    if (tid < s) sred[tid] = fmaxf(sred[tid], sred[tid + s]);
    __syncthreads();
  }
  float m = sred[0];
  __syncthreads();

  float4 e4 = {0.f, 0.f, 0.f, 0.f};
  if (tid < 128) {
    e4.x = __expf(sc.x - m);
    e4.y = __expf(sc.y - m);
    e4.z = __expf(sc.z - m);
    e4.w = __expf(sc.w - m);
    sred[tid] = e4.x + e4.y + e4.z + e4.w;
  }
  __syncthreads();
  for (int s = 64; s > 0; s >>= 1) {
    if (tid < s) sred[tid] += sred[tid + s];
    __syncthreads();
  }
  float inv = 1.f / sred[0];
  if (tid < 128) {
    float4 out;
    out.x = e4.x * inv; out.y = e4.y * inv; out.z = e4.z * inv; out.w = e4.w * inv;
    ((float4*)(alpha + (size_t)b * Nn))[tid] = out;
  }
}

// ---------------------------------------------------------------------------
// Kernel 3: Xt = alpha * X (output 0) and xtb = bf16(Xt)  (verified)
// ---------------------------------------------------------------------------
__global__ __launch_bounds__(256) void scale_kernel(const float* __restrict__ X,
                                                    const float* __restrict__ alpha,
                                                    float* __restrict__ Xt,
                                                    unsigned short* __restrict__ xtb) {
  size_t i = (size_t)blockIdx.x * 256 + threadIdx.x;
  size_t e = i * 4;
  int n = (int)(e & (Nn - 1));
  int brow = (int)(e >> 9);
  int b = brow >> 7;
  float4 x = ((const float4*)X)[i];
  float4 a = *(const float4*)(alpha + (size_t)b * Nn + n);
  float4 y;
  y.x = x.x * a.x; y.y = x.y * a.y; y.z = x.z * a.z; y.w = x.w * a.w;
  ((float4*)Xt)[i] = y;
  ushort4 u;
  u.x = f2bf(y.x); u.y = f2bf(y.y); u.z = f2bf(y.z); u.w = f2bf(y.w);
  ((ushort4*)xtb)[i] = u;
}

// ---------------------------------------------------------------------------
// Kernel 4 (FUSED gemm+lstm): producer-consumer wave specialization.
// One block per batch b (256 blocks = 256 CUs), 1024 threads / 16 waves.
//   L-waves (0-7): R1's verified 4-way k-split dot2 lstm — 85.5 µs alone,
//     ~28% SIMD issue utilization -> ~70% idle latency slots.
//   G-waves (8-15): fill those slots: compute G chunk c+1 = 16 t-rows x 512
//     (xtb[b] @ wb^T + bias, MFMA 16x16x32, frag/swizzle math cloned from
//     the verified gemm_bt) into an LDS double buffer while L consumes c.
// Shared s_barrier cadence: 16 barriers/chunk (one per lstm step), 9 chunks
// (G produces c=0..7, L consumes c-1=0..7). Role-split drains:
//   G-waves: s_waitcnt vmcnt(0) lgkmcnt(0)  (publish LDS-DMA + ds writes)
//   L-waves: s_waitcnt lgkmcnt(0) only      (Xe stores stay in flight)
// Race audit: Bs written at even intervals (producer vmcnt-drained before
// barrier) and read at odd (readers lgkm-drained before next write); Gq
// buffers alternate per chunk, written at i=15, read the following chunk.
// Eliminates: gemm dispatch, 64 MB G write + 33 MB G read, one boundary.
// LDS 144.5 KB (dynamic; >64KB static not portable): Bs 64K + As 16K +
// Gq 2x32K + h 512B. __launch_bounds__(1024,4) caps VGPR<=128 so the
// 16-wave block is residency-feasible (4 waves/SIMD).
// ---------------------------------------------------------------------------
__global__ __launch_bounds__(1024, 4) void fused_kernel(
    const unsigned short* __restrict__ xtb,
    const unsigned short* __restrict__ wb,
    const float* __restrict__ bias,
    const float* __restrict__ w_hh,
    float* __restrict__ Xe) {
  int b = blockIdx.x;
  int tid = threadIdx.x;
  int wid = tid >> 6;
  const bool isG = wid >= 8;
  int lane = tid & 63;
  int l15 = lane & 15;
  int quad = lane >> 4;

  extern __shared__ char smem[];
  unsigned short* Bs = (unsigned short*)smem;              // [512 n][8 chunks swz] 64 KB
  unsigned short* As = (unsigned short*)(smem + 65536);    // [16 m][64 chunks swz] 16 KB
  float*          Gq = (float*)(smem + 81920);             // [2][16][512]          64 KB
  unsigned short* h2s = (unsigned short*)(smem + 147456);  // [2][128] fp16         512 B

  // ---------------- L-wave persistent state (R1 verbatim) ----------------
  int u = tid >> 2;      // unit (valid for L)
  int q = tid & 3;       // k-quarter / gate slot
  h2v_t wreg[4][16];
  float c0 = 0.f;
  float* Xeb = Xe + (size_t)b * Tt * Hh;
  if (!isG) {
#pragma unroll
    for (int f = 0; f < 4; ++f) {
      const float4* wr = (const float4*)(w_hh + ((size_t)(f * 128 + u) * 128 + q * 32));
#pragma unroll
      for (int i = 0; i < 8; ++i) {
        float4 v = wr[i];
        wreg[f][2 * i]     = (h2v_t){(_Float16)v.x, (_Float16)v.y};
        wreg[f][2 * i + 1] = (h2v_t){(_Float16)v.z, (_Float16)v.w};
      }
    }
    if (tid < 128) h2s[tid] = 0;   // h0 = 0 (buffer 0)
  }

  // ---------------- G-wave persistent state ----------------
  int w8 = wid - 8;                // 0..7 (valid for G)
  int glane = tid - 512;           // 0..511
  int bbase[8];                    // B staging: global element offset per load
  int aoff0 = 0, aoff1 = 0;        // A staging offsets
  float bias4[4];
  int pos8_0 = (0 * 4 + quad) ^ (l15 & 7);   // read-side swizzle, kh=0
  int pos8_1 = (1 * 4 + quad) ^ (l15 & 7);   // kh=1
  if (isG) {
#pragma unroll
    for (int s = 0; s < 8; ++s) {
      int lc = s * 512 + glane;
      int row = lc >> 3, pos = lc & 7;
      int ch = pos ^ (row & 7);
      bbase[s] = row * 512 + ch * 8;
    }
    {
      int lc = glane;
      int row = lc >> 6, pos = lc & 63;
      int ch = (pos & ~7) | ((pos & 7) ^ (row & 7));
      aoff0 = row * 512 + ch * 8;
      lc = 512 + glane;
      row = lc >> 6; pos = lc & 63;
      ch = (pos & ~7) | ((pos & 7) ^ (row & 7));
      aoff1 = row * 512 + ch * 8;
    }
#pragma unroll
    for (int nf = 0; nf < 4; ++nf) bias4[nf] = bias[w8 * 64 + nf * 16 + l15];
  }
  floatx4 acc[4];

  __syncthreads();   // h2s[0] visible to all

  // ---------------- main loop: 9 chunks x 16 barrier intervals ------------
  for (int c = 0; c < 9; ++c) {
    const bool gact = isG && (c < 8);
    const bool lact = (!isG) && (c >= 1);
    const float* gsrc = Gq + (size_t)((c + 1) & 1) * 8192;   // chunk c-1
    float* gdst = Gq + (size_t)(c & 1) * 8192;               // chunk c
    const unsigned short* Asrc = xtb + (((size_t)b * 128 + c * 16) * 512);

#pragma unroll 2
    for (int i = 0; i < 16; ++i) {
      // ---- G-wave tasks ----
      if (gact) {
        if ((i & 1) == 0) {
          int kb = i >> 1;
          if (i == 0) {
            async_load16(Asrc + aoff0, &As[(w8 * 64) * 8]);
            async_load16(Asrc + aoff1, &As[(512 + w8 * 64) * 8]);
          }
#pragma unroll
          for (int s = 0; s < 8; ++s)
            async_load16(wb + bbase[s] + kb * 64, &Bs[(s * 512 + w8 * 64) * 8]);
        } else {
          int kb = i >> 1;
          if (kb == 0) {
#pragma unroll
            for (int nf = 0; nf < 4; ++nf) acc[nf] = (floatx4){0.f, 0.f, 0.f, 0.f};
          }
          short8 af0 = *(const short8*)(&As[l15 * 512 + (kb * 8 + pos8_0) * 8]);
          short8 af1 = *(const short8*)(&As[l15 * 512 + (kb * 8 + pos8_1) * 8]);
#pragma unroll
          for (int nf = 0; nf < 4; ++nf) {
            int brow = (w8 * 64 + nf * 16 + l15) * 64;
            short8 bf0 = *(const short8*)(&Bs[brow + pos8_0 * 8]);
            short8 bf1 = *(const short8*)(&Bs[brow + pos8_1 * 8]);
            acc[nf] = __builtin_amdgcn_mfma_f32_16x16x32_bf16(af0, bf0, acc[nf], 0, 0, 0);
            acc[nf] = __builtin_amdgcn_mfma_f32_16x16x32_bf16(af1, bf1, acc[nf], 0, 0, 0);
          }
          if (i == 15) {
#pragma unroll
            for (int nf = 0; nf < 4; ++nf) {
              int col = w8 * 64 + nf * 16 + l15;
#pragma unroll
              for (int r = 0; r < 4; ++r)
                gdst[(quad * 4 + r) * 512 + col] = acc[nf][r] + bias4[nf];
            }
          }
        }
      }

      // ---- L-wave lstm step (R1 verbatim; G from LDS) ----
      if (lact) {
        int t = (c - 1) * 16 + i;
        int cur = i & 1;   // t & 1 == i & 1 (16 even)
        const uint4* hp = (const uint4*)(&h2s[cur * 128]) + q * 4;
        uint4 ha = hp[0], hb = hp[1], hc = hp[2], hd = hp[3];
        float g_this = gsrc[i * 512 + q * 128 + u];

        float pg0 = (q == 0) ? g_this : 0.f;
        float pg1 = (q == 1) ? g_this : 0.f;
        float pg2 = (q == 2) ? g_this : 0.f;
        float pg3 = (q == 3) ? g_this : 0.f;

#define DOTK(HB, K2)                                                \
  {                                                                 \
    h2v_t hh = __builtin_bit_cast(h2v_t, (HB));                     \
    pg0 = FDOT2(hh, wreg[0][K2], pg0);                              \
    pg1 = FDOT2(hh, wreg[1][K2], pg1);                              \
    pg2 = FDOT2(hh, wreg[2][K2], pg2);                              \
    pg3 = FDOT2(hh, wreg[3][K2], pg3);                              \
  }
        DOTK(ha.x, 0)  DOTK(ha.y, 1)  DOTK(ha.z, 2)  DOTK(ha.w, 3)
        DOTK(hb.x, 4)  DOTK(hb.y, 5)  DOTK(hb.z, 6)  DOTK(hb.w, 7)
        DOTK(hc.x, 8)  DOTK(hc.y, 9)  DOTK(hc.z, 10) DOTK(hc.w, 11)
        DOTK(hd.x, 12) DOTK(hd.y, 13) DOTK(hd.z, 14) DOTK(hd.w, 15)
#undef DOTK

        pg0 += qperm<0xB1>(pg0); pg1 += qperm<0xB1>(pg1);
        pg2 += qperm<0xB1>(pg2); pg3 += qperm<0xB1>(pg3);
        pg0 += qperm<0x4E>(pg0); pg1 += qperm<0x4E>(pg1);
        pg2 += qperm<0x4E>(pg2); pg3 += qperm<0x4E>(pg3);

        float si = sigmoid_fast(pg0);
        float sf = sigmoid_fast(pg1);
        float tg = tanh_fast(pg2);
        float so = sigmoid_fast(pg3);
        c0 = sf * c0 + si * tg;
        float hv = so * tanh_fast(c0);

        if (q == 0) {
          Xeb[(size_t)t * Hh + u] = hv;                      // fire-and-forget
          h2s[(cur ^ 1) * 128 + u] = __builtin_bit_cast(unsigned short, (_Float16)hv);
        }
      }

      // ---- role-split barrier ----
      if (isG) {
        asm volatile("s_waitcnt vmcnt(0) lgkmcnt(0)" ::: "memory");
      } else {
        asm volatile("s_waitcnt lgkmcnt(0)" ::: "memory");
      }
      __builtin_amdgcn_s_barrier();
      asm volatile("" ::: "memory");
    }
  }
}

// ---------------------------------------------------------------------------
extern "C" void kernel_launch(void* const* d_in, const int* in_sizes, int n_in,
                              void* d_out, int out_size, void* d_ws, size_t ws_size,
                              hipStream_t stream) {
  const float* X      = (const float*)d_in[0];
  const float* attn_w = (const float*)d_in[1];
  // d_in[2] = attn_b: cancels in softmax, unused
  const float* w_ih   = (const float*)d_in[3];
  const float* w_hh   = (const float*)d_in[4];
  const float* b_ih   = (const float*)d_in[5];
  const float* b_hh   = (const float*)d_in[6];

  float* Xt = (float*)d_out;                                  // (B,T,N)
  float* Xe = (float*)d_out + (size_t)Bb * Tt * Nn;           // (B,T,H)

  char* ws = (char*)d_ws;
  float*          alpha = (float*)(ws);                        //   512 KB
  float*          bias  = (float*)(ws + 524288);               //     2 KB
  unsigned short* wb    = (unsigned short*)(ws + 526336);      //   512 KB
  unsigned short* xtb   = (unsigned short*)(ws + 1050624);     //    32 MB

  hipFuncSetAttribute(reinterpret_cast<const void*>(fused_kernel),
                      hipFuncAttributeMaxDynamicSharedMemorySize, 147968);

  prep_kernel<<<dim3(1024), dim3(256), 0, stream>>>(w_ih, b_ih, b_hh, wb, bias);
  alpha_kernel<<<dim3(Bb), dim3(512), 0, stream>>>(X, attn_w, alpha);
  scale_kernel<<<dim3(16384), dim3(256), 0, stream>>>(X, alpha, Xt, xtb);
  fused_kernel<<<dim3(Bb), dim3(1024), 147968, stream>>>(xtb, wb, bias, w_hh, Xe);
}

// Round 10
// 267.904 us; speedup vs baseline: 1.3843x; 1.3843x over previous
//
#include <hip/hip_runtime.h>
#include <hip/hip_bf16.h>

// Problem constants
#define Bb 256
#define Tt 128
#define Nn 512
#define Hh 128
// 4H = 512

typedef __attribute__((ext_vector_type(4))) float floatx4;
typedef __attribute__((ext_vector_type(8))) short short8;
typedef _Float16 h2v_t __attribute__((ext_vector_type(2)));

__device__ __forceinline__ unsigned short f2bf(float f) {
  unsigned u = __float_as_uint(f);
  u += 0x7fffu + ((u >> 16) & 1u);   // round-to-nearest-even
  return (unsigned short)(u >> 16);
}

// Fast activations: v_exp + v_rcp (~1ulp each) instead of IEEE div sequences.
__device__ __forceinline__ float sigmoid_fast(float x) {
  return __builtin_amdgcn_rcpf(1.f + __expf(-x));
}
__device__ __forceinline__ float tanh_fast(float x) {
  float e = __expf(2.f * x);                       // inf-safe
  return 1.f - 2.f * __builtin_amdgcn_rcpf(e + 1.f);
}

// Workgroup barrier that does NOT drain vmcnt: only LDS ops are waited.
// Global loads/stores issued before it stay in flight across the barrier.
__device__ __forceinline__ void lds_barrier() {
  asm volatile("s_waitcnt lgkmcnt(0)" ::: "memory");
  __builtin_amdgcn_s_barrier();
  asm volatile("" ::: "memory");
}

__device__ __forceinline__ void async_load16(const void* g, void* lds) {
  __builtin_amdgcn_global_load_lds(
      (const __attribute__((address_space(1))) unsigned int*)g,
      (__attribute__((address_space(3))) unsigned int*)lds, 16, 0, 0);
}

// 2-MAC-per-lane fp16 dot with fp32 accumulate (v_dot2_f32_f16).
#if __has_builtin(__builtin_amdgcn_fdot2)
#define FDOT2(a, b, c) __builtin_amdgcn_fdot2((a), (b), (c), false)
#else
__device__ __forceinline__ float fdot2_sw(h2v_t a, h2v_t b, float c) {
  return fmaf((float)a.x, (float)b.x, fmaf((float)a.y, (float)b.y, (c)));
}
#define FDOT2(a, b, c) fdot2_sw((a), (b), (c))
#endif

// Quad butterfly via DPP. 0xB1 = [1,0,3,2] (xor 1); 0x4E = [2,3,0,1] (xor 2).
// HW-verified R1/R8 (passing runs).
template <int CTRL>
__device__ __forceinline__ float qperm(float x) {
#if __has_builtin(__builtin_amdgcn_update_dpp)
  return __uint_as_float((unsigned)__builtin_amdgcn_update_dpp(
      0, (int)__float_as_uint(x), CTRL, 0xf, 0xf, true));
#else
  return __shfl_xor(x, CTRL == 0xB1 ? 1 : 2, 64);
#endif
}

// Quad broadcast via DPP quad_perm: 0x00/0x55/0xAA/0xFF broadcasts lane
// (quad_base + 0/1/2/3) to all 4 lanes. HW-verified in R2's passing run.
template <int CTRL>
__device__ __forceinline__ float qbcast(float x) {
#if __has_builtin(__builtin_amdgcn_update_dpp)
  return __uint_as_float((unsigned)__builtin_amdgcn_update_dpp(
      0, (int)__float_as_uint(x), CTRL, 0xf, 0xf, true));
#else
  return __shfl(x, (threadIdx.x & ~3) + (CTRL & 3), 64);
#endif
}

// ---------------------------------------------------------------------------
// Kernel 2 (+prep folded): alpha[b,n] = softmax_n( sum_t X[b,t,n] * w_x[t] )
// (softmax shift-invariance kills the h/c-dependent scalar term)
// Coalesced column loads (R4/R8-verified). Each thread also converts 2
// w_ih elements to bf16 and (first 512 global threads) computes bias —
// folds the former prep_kernel dispatch into this one.
// ---------------------------------------------------------------------------
__global__ __launch_bounds__(512) void alpha_kernel(const float* __restrict__ X,
                                                    const float* __restrict__ attn_w,
                                                    const float* __restrict__ w_ih,
                                                    const float* __restrict__ b_ih,
                                                    const float* __restrict__ b_hh,
                                                    float* __restrict__ alpha,
                                                    unsigned short* __restrict__ wb,
                                                    float* __restrict__ bias) {
  int b = blockIdx.x;
  int tid = threadIdx.x;

  // --- folded prep: 2 w_ih elements + (block 0) bias ---
  {
    int g = b * 512 + tid;                       // 131072 threads, 262144 elems
    float2 wv = *(const float2*)(w_ih + 2 * g);
    ushort2 wo;
    wo.x = f2bf(wv.x);
    wo.y = f2bf(wv.y);
    *(ushort2*)(wb + 2 * g) = wo;
    if (g < 4 * Hh) bias[g] = b_ih[g] + b_hh[g];
  }

  int c = tid & 127;        // float4 column index (n = 4c..4c+3)
  int tp = tid >> 7;        // 4-way t-split
  const float4* Xb = (const float4*)(X + (size_t)b * Tt * Nn) + c;
  const float* wx = attn_w + 2 * Hh;

  float4 acc = {0.f, 0.f, 0.f, 0.f};
#pragma unroll 8
  for (int tt = 0; tt < 32; ++tt) {
    int t = tp * 32 + tt;
    float4 x = Xb[(size_t)t * 128];
    float w = wx[t];
    acc.x = fmaf(x.x, w, acc.x);
    acc.y = fmaf(x.y, w, acc.y);
    acc.z = fmaf(x.z, w, acc.z);
    acc.w = fmaf(x.w, w, acc.w);
  }

  __shared__ float4 s4[512];     // 8 KB
  __shared__ float sred[128];
  s4[tid] = acc;
  __syncthreads();

  float4 sc = {0.f, 0.f, 0.f, 0.f};
  if (tid < 128) {
    float4 a = s4[tid], b2 = s4[tid + 128], c2 = s4[tid + 256], d = s4[tid + 384];
    sc.x = a.x + b2.x + c2.x + d.x;
    sc.y = a.y + b2.y + c2.y + d.y;
    sc.z = a.z + b2.z + c2.z + d.z;
    sc.w = a.w + b2.w + c2.w + d.w;
    sred[tid] = fmaxf(fmaxf(sc.x, sc.y), fmaxf(sc.z, sc.w));
  }
  __syncthreads();
  for (int s = 64; s > 0; s >>= 1) {
    if (tid < s) sred[tid] = fmaxf(sred[tid], sred[tid + s]);
    __syncthreads();
  }
  float m = sred[0];
  __syncthreads();

  float4 e4 = {0.f, 0.f, 0.f, 0.f};
  if (tid < 128) {
    e4.x = __expf(sc.x - m);
    e4.y = __expf(sc.y - m);
    e4.z = __expf(sc.z - m);
    e4.w = __expf(sc.w - m);
    sred[tid] = e4.x + e4.y + e4.z + e4.w;
  }
  __syncthreads();
  for (int s = 64; s > 0; s >>= 1) {
    if (tid < s) sred[tid] += sred[tid + s];
    __syncthreads();
  }
  float inv = 1.f / sred[0];     // one precise division per block
  if (tid < 128) {
    float4 out;
    out.x = e4.x * inv; out.y = e4.y * inv; out.z = e4.z * inv; out.w = e4.w * inv;
    ((float4*)(alpha + (size_t)b * Nn))[tid] = out;
  }
}

// ---------------------------------------------------------------------------
// Kernel 3: Xt = alpha * X (fp32, output 0) and xtb = bf16(Xt) for the GEMM
// Grid-stride: 2048 blocks x 8 float4/thread (G11) instead of 16384 blocks.
// ---------------------------------------------------------------------------
__global__ __launch_bounds__(256) void scale_kernel(const float* __restrict__ X,
                                                    const float* __restrict__ alpha,
                                                    float* __restrict__ Xt,
                                                    unsigned short* __restrict__ xtb) {
  size_t base = (size_t)blockIdx.x * 256 + threadIdx.x;
#pragma unroll
  for (int it = 0; it < 8; ++it) {
    size_t i = base + (size_t)it * 524288;            // 2048*256
    size_t e = i * 4;
    int n = (int)(e & (Nn - 1));
    int brow = (int)(e >> 9);   // b*T + t
    int b = brow >> 7;          // T = 128
    float4 x = ((const float4*)X)[i];
    float4 a = *(const float4*)(alpha + (size_t)b * Nn + n);
    float4 y;
    y.x = x.x * a.x; y.y = x.y * a.y; y.z = x.z * a.z; y.w = x.w * a.w;
    ((float4*)Xt)[i] = y;
    ushort4 u;
    u.x = f2bf(y.x); u.y = f2bf(y.y); u.z = f2bf(y.z); u.w = f2bf(y.w);
    ((ushort4*)xtb)[i] = u;
  }
}

// ---------------------------------------------------------------------------
// Kernel 4: G[m, j] = sum_k xtb[m,k] * w_ih[j,k] + bias[j]   (bf16 MFMA)
// M = B*T = 32768, N = 512, K = 512. B^T layout (w_ih rows are k-contiguous).
// 128x128 block tile, 4 waves 2x2, 64x64/wave via 4x4 frags of 16x16x32.
// Staging via global_load_lds (16B) into XOR-swizzled LDS. (verified)
// ---------------------------------------------------------------------------
#define GBK 64

__global__ __launch_bounds__(256) void gemm_bt(const unsigned short* __restrict__ A,
                                               const unsigned short* __restrict__ Bw,
                                               const float* __restrict__ bias,
                                               float* __restrict__ C) {
  __shared__ __align__(16) unsigned short As[128 * 64];
  __shared__ __align__(16) unsigned short Bs[128 * 64];
  const int K = 512, NO = 512;
  int tid = threadIdx.x;
  int lane = tid & 63;
  int wave = tid >> 6;
  int wm = wave & 1, wn = wave >> 1;
  int l15 = lane & 15;
  int quad = lane >> 4;
  int mtile = blockIdx.x, ntile = blockIdx.y;

  floatx4 acc[4][4];
#pragma unroll
  for (int i = 0; i < 4; ++i)
#pragma unroll
    for (int j = 0; j < 4; ++j) acc[i][j] = (floatx4){0.f, 0.f, 0.f, 0.f};

  // staging addresses
  int lr = lane >> 3;                 // local row within wave-slot (0..7)
  int lc = (lane & 7) ^ lr;           // swizzled global k-chunk for this lane
  const size_t lane_goff = (size_t)lr * K + lc * 8;
  const size_t abase = (size_t)mtile * 128 * K + lane_goff;
  const size_t bbase = (size_t)ntile * 128 * K + lane_goff;
  // MFMA read swizzle (lane-static)
  int sw = (quad ^ (l15 & 7)) * 8;    // element offset of chunk for kh=0

  for (int kb = 0; kb < K; kb += GBK) {
#pragma unroll
    for (int slot = 0; slot < 4; ++slot) {
      int r0 = slot * 32 + wave * 8;
      async_load16(A + abase + (size_t)r0 * K + kb, &As[r0 * 64]);
      async_load16(Bw + bbase + (size_t)r0 * K + kb, &Bs[r0 * 64]);
    }
    __syncthreads();   // drains vmcnt(0): LDS-DMA complete
#pragma unroll
    for (int kh = 0; kh < 2; ++kh) {
      int sc = sw ^ (kh * 32);        // ^ (4 chunks * 8 elem)
      short8 af[4], bf[4];
#pragma unroll
      for (int i = 0; i < 4; ++i)
        af[i] = *(const short8*)(&As[(wm * 64 + i * 16 + l15) * 64 + sc]);
#pragma unroll
      for (int j = 0; j < 4; ++j)
        bf[j] = *(const short8*)(&Bs[(wn * 64 + j * 16 + l15) * 64 + sc]);
#pragma unroll
      for (int i = 0; i < 4; ++i)
#pragma unroll
        for (int j = 0; j < 4; ++j)
          acc[i][j] = __builtin_amdgcn_mfma_f32_16x16x32_bf16(af[i], bf[j], acc[i][j], 0, 0, 0);
    }
    __syncthreads();
  }

  // Epilogue: C/D mapping col = lane&15 (n), row = quad*4 + reg (m)
  int m0 = mtile * 128 + wm * 64;
  int n0 = ntile * 128 + wn * 64;
#pragma unroll
  for (int j = 0; j < 4; ++j) {
    int col = n0 + j * 16 + l15;
    float bsum = bias[col];
#pragma unroll
    for (int i = 0; i < 4; ++i) {
      int row = m0 + i * 16 + quad * 4;
#pragma unroll
      for (int r = 0; r < 4; ++r)
        C[(size_t)(row + r) * NO + col] = acc[i][j][r] + bsum;
    }
  }
}

// ---------------------------------------------------------------------------
// Kernel 5: sequential LSTM — R1's 4-way k-split dot2 (85.5 µs verified)
// with TRANS-REDUCED activation: after the quad butterfly every lane holds
// all 4 gate sums; previously every lane ran all 4 activations (10 trans
// ops/thread; wave64 trans issues at 1/4 rate -> ~320 cyc/SIMD/step, ~20%
// of the 1600-cyc step). Now lane q activates only gate q via the unified
// form val = fma(rcp(1+exp(x*actm)), fA, fB) (sigmoid q!=2, tanh q==2),
// then 4 DPP qbcast (verified R2) distribute (si,sf,tg,so): 4 trans/thread.
// Everything else identical to the R8-verified kernel.
// Session record: 6 alternative structures (gate-split, ring, 8-way window,
// 16-batch MFMA, fused producer-consumer) all measured SLOWER; ~1600
// cyc/step is the 1-batch-per-CU barrier+latency path; do not re-derive.
// ---------------------------------------------------------------------------
__global__ __launch_bounds__(512, 1) void lstm_kernel(const float* __restrict__ G,
                                                      const float* __restrict__ w_hh,
                                                      float* __restrict__ Xe) {
  int b = blockIdx.x;
  int tid = threadIdx.x;
  int u = tid >> 2;      // unit 0..127
  int q = tid & 3;       // k-quarter / gate-bias slot

  // Preload this lane's w_hh slice: rows f*128+u, cols [32q, 32q+32), fp16.
  h2v_t wreg[4][16];
#pragma unroll
  for (int f = 0; f < 4; ++f) {
    const float4* wr = (const float4*)(w_hh + ((size_t)(f * 128 + u) * 128 + q * 32));
#pragma unroll
    for (int i = 0; i < 8; ++i) {
      float4 v = wr[i];
      wreg[f][2 * i]     = (h2v_t){(_Float16)v.x, (_Float16)v.y};
      wreg[f][2 * i + 1] = (h2v_t){(_Float16)v.z, (_Float16)v.w};
    }
  }

  __shared__ __align__(16) unsigned short h2[2][128];   // fp16 h, double-buffered
  if (tid < 128) h2[0][tid] = 0;
  __syncthreads();

  const float* Gb = G + (size_t)b * Tt * 512 + q * 128 + u;
  float* Xeb = Xe + (size_t)b * Tt * Hh;

  float gcur = Gb[0];
  float gnext = Gb[512];
  float c0 = 0.f;

  // Per-lane activation constants: q==2 -> tanh, else sigmoid (R2-verified).
  const float actm = (q == 2) ? 2.f : -1.f;
  const float fA   = (q == 2) ? -2.f : 1.f;
  const float fB   = (q == 2) ? 1.f : 0.f;

#define H2F(W) __builtin_bit_cast(h2v_t, (W))

  for (int t = 0; t < Tt; ++t) {
    int cur = t & 1;
    // Broadcast-read this lane's h quarter: bytes [64q, 64q+64) of buf[cur].
    const uint4* hp = (const uint4*)(&h2[cur][0]) + q * 4;
    uint4 ha = hp[0], hb = hp[1], hc = hp[2], hd = hp[3];

    float g_this = gcur;
    gcur = gnext;
    if (t + 2 < Tt) gnext = Gb[(size_t)(t + 2) * 512];   // in flight across barrier

    float pg0 = (q == 0) ? g_this : 0.f;
    float pg1 = (q == 1) ? g_this : 0.f;
    float pg2 = (q == 2) ? g_this : 0.f;
    float pg3 = (q == 3) ? g_this : 0.f;

#define DOTK(HB, K2)                                                \
  {                                                                 \
    h2v_t hh = __builtin_bit_cast(h2v_t, (HB));                     \
    pg0 = FDOT2(hh, wreg[0][K2], pg0);                              \
    pg1 = FDOT2(hh, wreg[1][K2], pg1);                              \
    pg2 = FDOT2(hh, wreg[2][K2], pg2);                              \
    pg3 = FDOT2(hh, wreg[3][K2], pg3);                              \
  }
    DOTK(ha.x, 0)  DOTK(ha.y, 1)  DOTK(ha.z, 2)  DOTK(ha.w, 3)
    DOTK(hb.x, 4)  DOTK(hb.y, 5)  DOTK(hb.z, 6)  DOTK(hb.w, 7)
    DOTK(hc.x, 8)  DOTK(hc.y, 9)  DOTK(hc.z, 10) DOTK(hc.w, 11)
    DOTK(hd.x, 12) DOTK(hd.y, 13) DOTK(hd.z, 14) DOTK(hd.w, 15)
#undef DOTK

    // Sum k-quarters across the 4 lanes of this quad (DPP butterfly).
    pg0 += qperm<0xB1>(pg0); pg1 += qperm<0xB1>(pg1);
    pg2 += qperm<0xB1>(pg2); pg3 += qperm<0xB1>(pg3);
    pg0 += qperm<0x4E>(pg0); pg1 += qperm<0x4E>(pg1);
    pg2 += qperm<0x4E>(pg2); pg3 += qperm<0x4E>(pg3);

    // Lane q activates gate q only (2 trans), then quad-broadcast.
    float x = (q == 0) ? pg0 : (q == 1) ? pg1 : (q == 2) ? pg2 : pg3;
    float e = __expf(x * actm);
    float val = fmaf(__builtin_amdgcn_rcpf(1.f + e), fA, fB);

    float gi = qbcast<0x00>(val);   // sigmoid(i)
    float gf = qbcast<0x55>(val);   // sigmoid(f)
    float gg = qbcast<0xAA>(val);   // tanh(g)
    float go = qbcast<0xFF>(val);   // sigmoid(o)

    c0 = fmaf(gf, c0, gi * gg);
    float hv = go * tanh_fast(c0);

    if (q == 0) {
      Xeb[(size_t)t * Hh + u] = hv;                       // fire-and-forget
      h2[cur ^ 1][u] = __builtin_bit_cast(unsigned short, (_Float16)hv);
    }
    lds_barrier();   // LDS-only drain; G loads / Xe stores stay in flight
  }
#undef H2F
}

// ---------------------------------------------------------------------------
extern "C" void kernel_launch(void* const* d_in, const int* in_sizes, int n_in,
                              void* d_out, int out_size, void* d_ws, size_t ws_size,
                              hipStream_t stream) {
  const float* X      = (const float*)d_in[0];
  const float* attn_w = (const float*)d_in[1];
  // d_in[2] = attn_b: cancels in softmax, unused
  const float* w_ih   = (const float*)d_in[3];
  const float* w_hh   = (const float*)d_in[4];
  const float* b_ih   = (const float*)d_in[5];
  const float* b_hh   = (const float*)d_in[6];

  float* Xt = (float*)d_out;                                  // (B,T,N)
  float* Xe = (float*)d_out + (size_t)Bb * Tt * Nn;           // (B,T,H)

  char* ws = (char*)d_ws;
  float*          alpha = (float*)(ws);                        //   512 KB
  float*          bias  = (float*)(ws + 524288);               //     2 KB
  unsigned short* wb    = (unsigned short*)(ws + 526336);      //   512 KB
  unsigned short* xtb   = (unsigned short*)(ws + 1050624);     //    32 MB
  float*          G     = (float*)(ws + 34605056);             //    64 MB
  // total ws use ~97 MB

  alpha_kernel<<<dim3(Bb), dim3(512), 0, stream>>>(X, attn_w, w_ih, b_ih, b_hh,
                                                   alpha, wb, bias);
  scale_kernel<<<dim3(2048), dim3(256), 0, stream>>>(X, alpha, Xt, xtb);
  gemm_bt<<<dim3(256, 4), dim3(256), 0, stream>>>(xtb, wb, bias, G);
  lstm_kernel<<<dim3(Bb), dim3(512), 0, stream>>>(G, w_hh, Xe);
}

// Round 11
// 260.844 us; speedup vs baseline: 1.4218x; 1.0271x over previous
//
#include <hip/hip_runtime.h>
#include <hip/hip_bf16.h>

// Problem constants
#define Bb 256
#define Tt 128
#define Nn 512
#define Hh 128
// 4H = 512

typedef __attribute__((ext_vector_type(4))) float floatx4;
typedef __attribute__((ext_vector_type(8))) short short8;
typedef _Float16 h2v_t __attribute__((ext_vector_type(2)));

__device__ __forceinline__ unsigned short f2bf(float f) {
  unsigned u = __float_as_uint(f);
  u += 0x7fffu + ((u >> 16) & 1u);   // round-to-nearest-even
  return (unsigned short)(u >> 16);
}

// Fast activations: v_exp + v_rcp (~1ulp each) instead of IEEE div sequences.
__device__ __forceinline__ float sigmoid_fast(float x) {
  return __builtin_amdgcn_rcpf(1.f + __expf(-x));
}
__device__ __forceinline__ float tanh_fast(float x) {
  float e = __expf(2.f * x);                       // inf-safe
  return 1.f - 2.f * __builtin_amdgcn_rcpf(e + 1.f);
}

// Workgroup barrier that does NOT drain vmcnt: only LDS ops are waited.
// Global loads/stores issued before it stay in flight across the barrier.
__device__ __forceinline__ void lds_barrier() {
  asm volatile("s_waitcnt lgkmcnt(0)" ::: "memory");
  __builtin_amdgcn_s_barrier();
  asm volatile("" ::: "memory");
}

__device__ __forceinline__ void async_load16(const void* g, void* lds) {
  __builtin_amdgcn_global_load_lds(
      (const __attribute__((address_space(1))) unsigned int*)g,
      (__attribute__((address_space(3))) unsigned int*)lds, 16, 0, 0);
}

// Pack 2 fp32 -> 1 word of 2 bf16 (RTNE). gfx950 ISA; HW-verified m214v22.
// src0 -> low 16 bits (ascending-k order for little-endian bf16 pairs).
__device__ __forceinline__ unsigned cvt_pk_bf16(float lo, float hi) {
  unsigned r;
  asm("v_cvt_pk_bf16_f32 %0, %1, %2" : "=v"(r) : "v"(lo), "v"(hi));
  return r;
}

// 2-MAC-per-lane fp16 dot with fp32 accumulate (v_dot2_f32_f16).
#if __has_builtin(__builtin_amdgcn_fdot2)
#define FDOT2(a, b, c) __builtin_amdgcn_fdot2((a), (b), (c), false)
#else
__device__ __forceinline__ float fdot2_sw(h2v_t a, h2v_t b, float c) {
  return fmaf((float)a.x, (float)b.x, fmaf((float)a.y, (float)b.y, (c)));
}
#define FDOT2(a, b, c) fdot2_sw((a), (b), (c))
#endif

// Quad butterfly via DPP. 0xB1 = [1,0,3,2] (xor 1); 0x4E = [2,3,0,1] (xor 2).
// HW-verified R1/R8 (passing runs).
template <int CTRL>
__device__ __forceinline__ float qperm(float x) {
#if __has_builtin(__builtin_amdgcn_update_dpp)
  return __uint_as_float((unsigned)__builtin_amdgcn_update_dpp(
      0, (int)__float_as_uint(x), CTRL, 0xf, 0xf, true));
#else
  return __shfl_xor(x, CTRL == 0xB1 ? 1 : 2, 64);
#endif
}

// Quad broadcast via DPP quad_perm: 0x00/0x55/0xAA/0xFF broadcasts lane
// (quad_base + 0/1/2/3) to all 4 lanes. HW-verified R2/R10 (passing runs).
template <int CTRL>
__device__ __forceinline__ float qbcast(float x) {
#if __has_builtin(__builtin_amdgcn_update_dpp)
  return __uint_as_float((unsigned)__builtin_amdgcn_update_dpp(
      0, (int)__float_as_uint(x), CTRL, 0xf, 0xf, true));
#else
  return __shfl(x, (threadIdx.x & ~3) + (CTRL & 3), 64);
#endif
}

// ---------------------------------------------------------------------------
// Kernel 1 (+prep folded): alpha[b,n] = softmax_n( sum_t X[b,t,n] * w_x[t] )
// (softmax shift-invariance kills the h/c-dependent scalar term)
// Coalesced column loads (R4/R8/R10-verified). Each thread also converts 2
// w_ih elements to bf16 and (first 512 global threads) computes bias.
// ---------------------------------------------------------------------------
__global__ __launch_bounds__(512) void alpha_kernel(const float* __restrict__ X,
                                                    const float* __restrict__ attn_w,
                                                    const float* __restrict__ w_ih,
                                                    const float* __restrict__ b_ih,
                                                    const float* __restrict__ b_hh,
                                                    float* __restrict__ alpha,
                                                    unsigned short* __restrict__ wb,
                                                    float* __restrict__ bias) {
  int b = blockIdx.x;
  int tid = threadIdx.x;

  // --- folded prep: 2 w_ih elements + (block 0) bias ---
  {
    int g = b * 512 + tid;                       // 131072 threads, 262144 elems
    float2 wv = *(const float2*)(w_ih + 2 * g);
    ushort2 wo;
    wo.x = f2bf(wv.x);
    wo.y = f2bf(wv.y);
    *(ushort2*)(wb + 2 * g) = wo;
    if (g < 4 * Hh) bias[g] = b_ih[g] + b_hh[g];
  }

  int c = tid & 127;        // float4 column index (n = 4c..4c+3)
  int tp = tid >> 7;        // 4-way t-split
  const float4* Xb = (const float4*)(X + (size_t)b * Tt * Nn) + c;
  const float* wx = attn_w + 2 * Hh;

  float4 acc = {0.f, 0.f, 0.f, 0.f};
#pragma unroll 8
  for (int tt = 0; tt < 32; ++tt) {
    int t = tp * 32 + tt;
    float4 x = Xb[(size_t)t * 128];
    float w = wx[t];
    acc.x = fmaf(x.x, w, acc.x);
    acc.y = fmaf(x.y, w, acc.y);
    acc.z = fmaf(x.z, w, acc.z);
    acc.w = fmaf(x.w, w, acc.w);
  }

  __shared__ float4 s4[512];     // 8 KB
  __shared__ float sred[128];
  s4[tid] = acc;
  __syncthreads();

  float4 sc = {0.f, 0.f, 0.f, 0.f};
  if (tid < 128) {
    float4 a = s4[tid], b2 = s4[tid + 128], c2 = s4[tid + 256], d = s4[tid + 384];
    sc.x = a.x + b2.x + c2.x + d.x;
    sc.y = a.y + b2.y + c2.y + d.y;
    sc.z = a.z + b2.z + c2.z + d.z;
    sc.w = a.w + b2.w + c2.w + d.w;
    sred[tid] = fmaxf(fmaxf(sc.x, sc.y), fmaxf(sc.z, sc.w));
  }
  __syncthreads();
  for (int s = 64; s > 0; s >>= 1) {
    if (tid < s) sred[tid] = fmaxf(sred[tid], sred[tid + s]);
    __syncthreads();
  }
  float m = sred[0];
  __syncthreads();

  float4 e4 = {0.f, 0.f, 0.f, 0.f};
  if (tid < 128) {
    e4.x = __expf(sc.x - m);
    e4.y = __expf(sc.y - m);
    e4.z = __expf(sc.z - m);
    e4.w = __expf(sc.w - m);
    sred[tid] = e4.x + e4.y + e4.z + e4.w;
  }
  __syncthreads();
  for (int s = 64; s > 0; s >>= 1) {
    if (tid < s) sred[tid] += sred[tid + s];
    __syncthreads();
  }
  float inv = 1.f / sred[0];     // one precise division per block
  if (tid < 128) {
    float4 out;
    out.x = e4.x * inv; out.y = e4.y * inv; out.z = e4.z * inv; out.w = e4.w * inv;
    ((float4*)(alpha + (size_t)b * Nn))[tid] = out;
  }
}

// ---------------------------------------------------------------------------
// Kernel 2 (FUSED scale+gemm): G[m,j] = sum_k (alpha[b,k]*X[m,k]) * wb[j,k]
// + bias[j], and Xt = alpha*X (fp32, output 0) written by ntile==0 blocks.
// Key identity: mtile == batch b (M-tile 128 rows = batch b's 128 t-rows),
// so alpha slice is block-uniform (2 KB in LDS). A is reg-staged: 8 coalesced
// float4 X loads/thread/k-iter (X is L3-resident after alpha's pass), one
// alpha float4 ds_read (thread's k-window is slot-invariant -> reused x8),
// 4 muls + 2 cvt_pk_bf16 + ds_write_b64 per chunk into the CANONICAL As
// layout of the harness-verified gemm_bt (LDS chunk cb of row r holds global
// chunk cb^(r&7); write-side XOR, read path verbatim). B staging, MFMA loop
// and epilogue are verbatim from the verified gemm_bt.
// Eliminates: scale dispatch, xtb (32 MB write + 32 MB read), one boundary.
// ---------------------------------------------------------------------------
#define GBK 64

__global__ __launch_bounds__(256) void gemm_fused(const float* __restrict__ X,
                                                  const float* __restrict__ alpha,
                                                  const unsigned short* __restrict__ Bw,
                                                  const float* __restrict__ bias,
                                                  float* __restrict__ Xt,
                                                  float* __restrict__ C) {
  __shared__ __align__(16) unsigned short As[128 * 64];
  __shared__ __align__(16) unsigned short Bs[128 * 64];
  __shared__ __align__(16) float sal[512];
  const int K = 512, NO = 512;
  int tid = threadIdx.x;
  int lane = tid & 63;
  int wave = tid >> 6;
  int wm = wave & 1, wn = wave >> 1;
  int l15 = lane & 15;
  int quad = lane >> 4;
  int mtile = blockIdx.x, ntile = blockIdx.y;   // mtile == batch b

  // Stage alpha[b, :512] (block-uniform, 2 KB).
  ((float2*)sal)[tid] = ((const float2*)(alpha + (size_t)mtile * Nn))[tid];

  floatx4 acc[4][4];
#pragma unroll
  for (int i = 0; i < 4; ++i)
#pragma unroll
    for (int j = 0; j < 4; ++j) acc[i][j] = (floatx4){0.f, 0.f, 0.f, 0.f};

  // ---- A (reg-staged): slot s covers rows s*16 + wave*4 + (lane>>4) ----
  int ar = wave * 4 + (lane >> 4);    // row-within-slot-group (0..15)
  int c4 = l15;                       // fp32 chunk 0..15 (floats [4c4,4c4+4))
  const float4* X4 = (const float4*)X + ((size_t)mtile * 128) * 128 + c4;
  float4* Xt4 = Xt ? (float4*)Xt + ((size_t)mtile * 128) * 128 + c4 : nullptr;
  const bool writeXt = (ntile == 0);

  // ---- B (global_load_lds, verbatim gemm_bt) ----
  int lr = lane >> 3;                 // local row within wave-slot (0..7)
  int lc = (lane & 7) ^ lr;           // swizzled global k-chunk for this lane
  const size_t bbase = (size_t)ntile * 128 * K + (size_t)lr * K + lc * 8;
  // MFMA read swizzle (lane-static, verbatim)
  int sw = (quad ^ (l15 & 7)) * 8;

  __syncthreads();   // sal visible

  for (int kb = 0; kb < K; kb += GBK) {
    // Issue A register loads (8 rows: slot s -> row s*16 + ar).
    float4 areg[8];
#pragma unroll
    for (int s = 0; s < 8; ++s)
      areg[s] = X4[(size_t)(s * 16 + ar) * 128 + (kb >> 2)];
    // Issue B LDS-DMA (verbatim).
#pragma unroll
    for (int slot = 0; slot < 4; ++slot) {
      int r0 = slot * 32 + wave * 8;
      async_load16(Bw + bbase + (size_t)r0 * K + kb, &Bs[r0 * 64]);
    }
    // alpha window for this thread (same for all 8 slots).
    float4 av = *(const float4*)(&sal[kb + c4 * 4]);
    // Convert + scatter to canonical As (+ Xt store from ntile 0).
#pragma unroll
    for (int s = 0; s < 8; ++s) {
      int r = s * 16 + ar;
      float4 v = areg[s];
      float4 p;
      p.x = v.x * av.x; p.y = v.y * av.y; p.z = v.z * av.z; p.w = v.w * av.w;
      if (writeXt) Xt4[(size_t)r * 128 + (kb >> 2)] = p;
      uint2 pk;
      pk.x = cvt_pk_bf16(p.x, p.y);
      pk.y = cvt_pk_bf16(p.z, p.w);
      // LDS byte = r*128 + ((c4>>1)^(r&7))*16 + (c4&1)*8  (canonical swizzle)
      *(uint2*)((char*)As + r * 128 + ((((c4 >> 1) ^ (r & 7)) << 4) | ((c4 & 1) << 3))) = pk;
    }
    __syncthreads();   // drains vmcnt (B DMA) + lgkm (As writes)
#pragma unroll
    for (int kh = 0; kh < 2; ++kh) {
      int sc = sw ^ (kh * 32);
      short8 af[4], bf[4];
#pragma unroll
      for (int i = 0; i < 4; ++i)
        af[i] = *(const short8*)(&As[(wm * 64 + i * 16 + l15) * 64 + sc]);
#pragma unroll
      for (int j = 0; j < 4; ++j)
        bf[j] = *(const short8*)(&Bs[(wn * 64 + j * 16 + l15) * 64 + sc]);
#pragma unroll
      for (int i = 0; i < 4; ++i)
#pragma unroll
        for (int j = 0; j < 4; ++j)
          acc[i][j] = __builtin_amdgcn_mfma_f32_16x16x32_bf16(af[i], bf[j], acc[i][j], 0, 0, 0);
    }
    __syncthreads();
  }

  // Epilogue: C/D mapping col = lane&15 (n), row = quad*4 + reg (m) (verbatim)
  int m0 = mtile * 128 + wm * 64;
  int n0 = ntile * 128 + wn * 64;
#pragma unroll
  for (int j = 0; j < 4; ++j) {
    int col = n0 + j * 16 + l15;
    float bsum = bias[col];
#pragma unroll
    for (int i = 0; i < 4; ++i) {
      int row = m0 + i * 16 + quad * 4;
#pragma unroll
      for (int r = 0; r < 4; ++r)
        C[(size_t)(row + r) * NO + col] = acc[i][j][r] + bsum;
    }
  }
}

// ---------------------------------------------------------------------------
// Kernel 3: sequential LSTM — R1 4-way k-split dot2 + R10 trans-reduced
// activation (79.8 µs verified R10). Session record: 6 alternative
// structures all measured SLOWER; ~1500 cyc/step is the 1-batch-per-CU
// barrier+latency path; do not re-derive.
// ---------------------------------------------------------------------------
__global__ __launch_bounds__(512, 1) void lstm_kernel(const float* __restrict__ G,
                                                      const float* __restrict__ w_hh,
                                                      float* __restrict__ Xe) {
  int b = blockIdx.x;
  int tid = threadIdx.x;
  int u = tid >> 2;      // unit 0..127
  int q = tid & 3;       // k-quarter / gate-bias slot

  // Preload this lane's w_hh slice: rows f*128+u, cols [32q, 32q+32), fp16.
  h2v_t wreg[4][16];
#pragma unroll
  for (int f = 0; f < 4; ++f) {
    const float4* wr = (const float4*)(w_hh + ((size_t)(f * 128 + u) * 128 + q * 32));
#pragma unroll
    for (int i = 0; i < 8; ++i) {
      float4 v = wr[i];
      wreg[f][2 * i]     = (h2v_t){(_Float16)v.x, (_Float16)v.y};
      wreg[f][2 * i + 1] = (h2v_t){(_Float16)v.z, (_Float16)v.w};
    }
  }

  __shared__ __align__(16) unsigned short h2[2][128];   // fp16 h, double-buffered
  if (tid < 128) h2[0][tid] = 0;
  __syncthreads();

  const float* Gb = G + (size_t)b * Tt * 512 + q * 128 + u;
  float* Xeb = Xe + (size_t)b * Tt * Hh;

  float gcur = Gb[0];
  float gnext = Gb[512];
  float c0 = 0.f;

  // Per-lane activation constants: q==2 -> tanh, else sigmoid.
  const float actm = (q == 2) ? 2.f : -1.f;
  const float fA   = (q == 2) ? -2.f : 1.f;
  const float fB   = (q == 2) ? 1.f : 0.f;

#define H2F(W) __builtin_bit_cast(h2v_t, (W))

  for (int t = 0; t < Tt; ++t) {
    int cur = t & 1;
    // Broadcast-read this lane's h quarter: bytes [64q, 64q+64) of buf[cur].
    const uint4* hp = (const uint4*)(&h2[cur][0]) + q * 4;
    uint4 ha = hp[0], hb = hp[1], hc = hp[2], hd = hp[3];

    float g_this = gcur;
    gcur = gnext;
    if (t + 2 < Tt) gnext = Gb[(size_t)(t + 2) * 512];   // in flight across barrier

    float pg0 = (q == 0) ? g_this : 0.f;
    float pg1 = (q == 1) ? g_this : 0.f;
    float pg2 = (q == 2) ? g_this : 0.f;
    float pg3 = (q == 3) ? g_this : 0.f;

#define DOTK(HB, K2)                                                \
  {                                                                 \
    h2v_t hh = __builtin_bit_cast(h2v_t, (HB));                     \
    pg0 = FDOT2(hh, wreg[0][K2], pg0);                              \
    pg1 = FDOT2(hh, wreg[1][K2], pg1);                              \
    pg2 = FDOT2(hh, wreg[2][K2], pg2);                              \
    pg3 = FDOT2(hh, wreg[3][K2], pg3);                              \
  }
    DOTK(ha.x, 0)  DOTK(ha.y, 1)  DOTK(ha.z, 2)  DOTK(ha.w, 3)
    DOTK(hb.x, 4)  DOTK(hb.y, 5)  DOTK(hb.z, 6)  DOTK(hb.w, 7)
    DOTK(hc.x, 8)  DOTK(hc.y, 9)  DOTK(hc.z, 10) DOTK(hc.w, 11)
    DOTK(hd.x, 12) DOTK(hd.y, 13) DOTK(hd.z, 14) DOTK(hd.w, 15)
#undef DOTK

    // Sum k-quarters across the 4 lanes of this quad (DPP butterfly).
    pg0 += qperm<0xB1>(pg0); pg1 += qperm<0xB1>(pg1);
    pg2 += qperm<0xB1>(pg2); pg3 += qperm<0xB1>(pg3);
    pg0 += qperm<0x4E>(pg0); pg1 += qperm<0x4E>(pg1);
    pg2 += qperm<0x4E>(pg2); pg3 += qperm<0x4E>(pg3);

    // Lane q activates gate q only (2 trans), then quad-broadcast.
    float x = (q == 0) ? pg0 : (q == 1) ? pg1 : (q == 2) ? pg2 : pg3;
    float e = __expf(x * actm);
    float val = fmaf(__builtin_amdgcn_rcpf(1.f + e), fA, fB);

    float gi = qbcast<0x00>(val);   // sigmoid(i)
    float gf = qbcast<0x55>(val);   // sigmoid(f)
    float gg = qbcast<0xAA>(val);   // tanh(g)
    float go = qbcast<0xFF>(val);   // sigmoid(o)

    c0 = fmaf(gf, c0, gi * gg);
    float hv = go * tanh_fast(c0);

    if (q == 0) {
      Xeb[(size_t)t * Hh + u] = hv;                       // fire-and-forget
      h2[cur ^ 1][u] = __builtin_bit_cast(unsigned short, (_Float16)hv);
    }
    lds_barrier();   // LDS-only drain; G loads / Xe stores stay in flight
  }
#undef H2F
}

// ---------------------------------------------------------------------------
extern "C" void kernel_launch(void* const* d_in, const int* in_sizes, int n_in,
                              void* d_out, int out_size, void* d_ws, size_t ws_size,
                              hipStream_t stream) {
  const float* X      = (const float*)d_in[0];
  const float* attn_w = (const float*)d_in[1];
  // d_in[2] = attn_b: cancels in softmax, unused
  const float* w_ih   = (const float*)d_in[3];
  const float* w_hh   = (const float*)d_in[4];
  const float* b_ih   = (const float*)d_in[5];
  const float* b_hh   = (const float*)d_in[6];

  float* Xt = (float*)d_out;                                  // (B,T,N)
  float* Xe = (float*)d_out + (size_t)Bb * Tt * Nn;           // (B,T,H)

  char* ws = (char*)d_ws;
  float*          alpha = (float*)(ws);                        //   512 KB
  float*          bias  = (float*)(ws + 524288);               //     2 KB
  unsigned short* wb    = (unsigned short*)(ws + 526336);      //   512 KB
  float*          G     = (float*)(ws + 34605056);             //    64 MB

  alpha_kernel<<<dim3(Bb), dim3(512), 0, stream>>>(X, attn_w, w_ih, b_ih, b_hh,
                                                   alpha, wb, bias);
  gemm_fused<<<dim3(256, 4), dim3(256), 0, stream>>>(X, alpha, wb, bias, Xt, G);
  lstm_kernel<<<dim3(Bb), dim3(512), 0, stream>>>(G, w_hh, Xe);
}